// Round 1
// baseline (64.113 us; speedup 1.0000x reference)
//
#include <hip/hip_runtime.h>
#include <hip/hip_bf16.h>
#include <math.h>

#define D_MODEL 1024
#define LSEQ 2048
#define BATCH 2
#define NROWS (BATCH*LSEQ)   // 4096
#define NC 16                // decay-sum chunks along L
#define CHS (LSEQ/NC)        // 128

typedef __bf16 bf16;
typedef __attribute__((ext_vector_type(8))) __bf16 bf16x8;
typedef __attribute__((ext_vector_type(4))) __bf16 bf16x4;
typedef __attribute__((ext_vector_type(4))) float f32x4;

__device__ __forceinline__ float sigA(float ap) {
    float A = 1.0f / (1.0f + expf(-ap));
    // guard against A==0 (log2f(0)=-inf -> 0*inf NaN); sigmoid<=1 already
    return fmaxf(A, 1e-30f);
}

// ---------------- K1: chunked decay partial sums  P_c[b,c,d] = sum_{s in chunk c} A^s x[b,s,d]
__global__ __launch_bounds__(256) void k_decay(const float* __restrict__ x,
                                               const float* __restrict__ A_param,
                                               float* __restrict__ partial) {
    const int c = blockIdx.x, dg = blockIdx.y, b = blockIdx.z;
    const int d = dg * 256 + threadIdx.x;
    const float A = sigA(A_param[d]);
    const float l2A = log2f(A);
    const int s0 = c * CHS;
    float sum = 0.0f;
    // if the largest weight in this chunk underflows to 0, whole chunk is exactly 0
    if (exp2f((float)s0 * l2A) != 0.0f) {
        const float* xp = x + ((size_t)b * LSEQ + s0) * D_MODEL + d;
        #pragma unroll 4
        for (int j = 0; j < CHS; ++j) {
            float w = exp2f((float)(s0 + j) * l2A);
            sum += w * xp[(size_t)j * D_MODEL];
        }
    }
    partial[((size_t)b * NC + c) * D_MODEL + d] = sum;
}

// ---------------- K2: W f32 -> bf16
__global__ __launch_bounds__(256) void k_wcast(const float* __restrict__ W, bf16* __restrict__ Wb) {
    int idx = (blockIdx.x * 256 + threadIdx.x) * 4;   // D*D = 1M, exact
    float4 v = *reinterpret_cast<const float4*>(W + idx);
    bf16x4 o;
    o.x = (bf16)v.x; o.y = (bf16)v.y; o.z = (bf16)v.z; o.w = (bf16)v.w;
    *reinterpret_cast<bf16x4*>(Wb + idx) = o;
}

// ---------------- K3: conv closed-form + skip + exact GELU -> bf16 G (GEMM A-matrix)
__global__ __launch_bounds__(256) void k_prep(const float* __restrict__ x,
                                              const float* __restrict__ A_param,
                                              const float* __restrict__ Bv,
                                              const float* __restrict__ Cv,
                                              const float* __restrict__ Dv,
                                              const float* __restrict__ partial,
                                              bf16* __restrict__ G) {
    const int ic = blockIdx.x, dg = blockIdx.y, b = blockIdx.z;
    const int d = dg * 256 + threadIdx.x;
    const float A = sigA(A_param[d]);
    const float l2A = log2f(A);
    float P = 0.0f;
    #pragma unroll
    for (int c = 0; c < NC; ++c) P += partial[((size_t)b * NC + c) * D_MODEL + d];
    const float coeff = Cv[d] * Bv[d] * P;
    const float dv = Dv[d];
    const int i0 = ic * 64;
    #pragma unroll 4
    for (int j = 0; j < 64; ++j) {
        const int i = i0 + j;
        float conv = coeff * exp2f((float)(LSEQ - 1 - i) * l2A);
        float u = conv + dv * x[((size_t)b * LSEQ + i) * D_MODEL + d];
        float g = 0.5f * u * (1.0f + erff(u * 0.70710678118654752f));
        G[((size_t)b * LSEQ + i) * D_MODEL + d] = (bf16)g;
    }
}

// ---------------- K4: Y = G @ Wb^T + bias   (M=4096, N=K=1024, bf16 MFMA 16x16x32)
__global__ __launch_bounds__(256) void k_gemm(const bf16* __restrict__ G,
                                              const bf16* __restrict__ Wb,
                                              const float* __restrict__ bias,
                                              float* __restrict__ Y) {
    constexpr int TM = 128, TN = 128, BK = 32, K = D_MODEL, N = D_MODEL;
    __shared__ __align__(16) bf16 As[TM][BK];
    __shared__ __align__(16) bf16 Bs[TN][BK];
    const int tid = threadIdx.x;
    const int lane = tid & 63, wave = tid >> 6;
    const int row0 = blockIdx.x * TM, col0 = blockIdx.y * TN;
    const int wm = (wave >> 1) * 64, wn = (wave & 1) * 64;
    f32x4 acc[4][4] = {};

    const int mr = lane & 15;
    const int kr = (lane >> 4) * 8;

    for (int k0 = 0; k0 < K; k0 += BK) {
        #pragma unroll
        for (int r = 0; r < 2; ++r) {
            int f = (tid + r * 256) * 8;       // flat bf16 index in tile
            int trow = f >> 5, tcol = f & 31;  // [128][32]
            bf16x8 av = *reinterpret_cast<const bf16x8*>(G  + (size_t)(row0 + trow) * K + k0 + tcol);
            bf16x8 bv = *reinterpret_cast<const bf16x8*>(Wb + (size_t)(col0 + trow) * K + k0 + tcol);
            *reinterpret_cast<bf16x8*>(&As[trow][tcol]) = av;
            *reinterpret_cast<bf16x8*>(&Bs[trow][tcol]) = bv;
        }
        __syncthreads();
        bf16x8 a[4], bb[4];
        #pragma unroll
        for (int f = 0; f < 4; ++f) a[f]  = *reinterpret_cast<const bf16x8*>(&As[wm + f * 16 + mr][kr]);
        #pragma unroll
        for (int f = 0; f < 4; ++f) bb[f] = *reinterpret_cast<const bf16x8*>(&Bs[wn + f * 16 + mr][kr]);
        #pragma unroll
        for (int fm = 0; fm < 4; ++fm)
            #pragma unroll
            for (int fn = 0; fn < 4; ++fn)
                acc[fm][fn] = __builtin_amdgcn_mfma_f32_16x16x32_bf16(a[fm], bb[fn], acc[fm][fn], 0, 0, 0);
        __syncthreads();
    }
    // epilogue: C/D layout col = lane&15, row = (lane>>4)*4 + reg
    #pragma unroll
    for (int fm = 0; fm < 4; ++fm) {
        int mbase = row0 + wm + fm * 16 + (lane >> 4) * 4;
        #pragma unroll
        for (int fn = 0; fn < 4; ++fn) {
            int n = col0 + wn + fn * 16 + (lane & 15);
            float bv = bias[n];
            #pragma unroll
            for (int r = 0; r < 4; ++r)
                Y[(size_t)(mbase + r) * N + n] = acc[fm][fn][r] + bv;
        }
    }
}

// ---------------- K5: out = LayerNorm(x + Y) * gamma + beta   (in-place on Y==d_out)
__global__ __launch_bounds__(256) void k_ln(const float* __restrict__ x,
                                            const float* __restrict__ gamma,
                                            const float* __restrict__ beta,
                                            float* __restrict__ out) {
    const int row = blockIdx.x;
    const int t = threadIdx.x;
    const float* xr = x + (size_t)row * D_MODEL;
    float* yr = out + (size_t)row * D_MODEL;
    float z[4]; float s = 0.0f, sq = 0.0f;
    #pragma unroll
    for (int j = 0; j < 4; ++j) {
        int d = t + j * 256;
        float v = xr[d] + yr[d];
        z[j] = v; s += v; sq += v * v;
    }
    #pragma unroll
    for (int o = 1; o < 64; o <<= 1) { s += __shfl_xor(s, o, 64); sq += __shfl_xor(sq, o, 64); }
    __shared__ float ls[4], lq[4];
    int wave = t >> 6;
    if ((t & 63) == 0) { ls[wave] = s; lq[wave] = sq; }
    __syncthreads();
    s = ls[0] + ls[1] + ls[2] + ls[3];
    sq = lq[0] + lq[1] + lq[2] + lq[3];
    const float mu = s * (1.0f / D_MODEL);
    const float var = sq * (1.0f / D_MODEL) - mu * mu;
    const float inv = rsqrtf(var + 1e-5f);
    #pragma unroll
    for (int j = 0; j < 4; ++j) {
        int d = t + j * 256;
        yr[d] = (z[j] - mu) * inv * gamma[d] + beta[d];
    }
}

extern "C" void kernel_launch(void* const* d_in, const int* in_sizes, int n_in,
                              void* d_out, int out_size, void* d_ws, size_t ws_size,
                              hipStream_t stream) {
    const float* x       = (const float*)d_in[0];
    const float* A_param = (const float*)d_in[1];
    const float* B_vec   = (const float*)d_in[2];
    const float* C_vec   = (const float*)d_in[3];
    const float* D_vec   = (const float*)d_in[4];
    const float* W       = (const float*)d_in[5];
    const float* b_proj  = (const float*)d_in[6];
    const float* gamma   = (const float*)d_in[7];
    const float* beta    = (const float*)d_in[8];
    float* out = (float*)d_out;

    char* ws = (char*)d_ws;
    float* partial = (float*)ws;                               // 2*16*1024*4   = 128 KiB
    bf16*  Wb      = (bf16*)(ws + (128 << 10));                // 1024*1024*2   = 2 MiB
    bf16*  G       = (bf16*)(ws + (128 << 10) + (2 << 20));    // 4096*1024*2   = 8 MiB

    hipLaunchKernelGGL(k_decay, dim3(NC, D_MODEL / 256, BATCH), dim3(256), 0, stream, x, A_param, partial);
    hipLaunchKernelGGL(k_wcast, dim3(D_MODEL * D_MODEL / 1024), dim3(256), 0, stream, W, Wb);
    hipLaunchKernelGGL(k_prep,  dim3(LSEQ / 64, D_MODEL / 256, BATCH), dim3(256), 0, stream,
                       x, A_param, B_vec, C_vec, D_vec, partial, G);
    hipLaunchKernelGGL(k_gemm,  dim3(NROWS / 128, D_MODEL / 128), dim3(256), 0, stream, G, Wb, b_proj, out);
    hipLaunchKernelGGL(k_ln,    dim3(NROWS), dim3(256), 0, stream, x, gamma, beta, out);
}

// Round 2
// 55.405 us; speedup vs baseline: 1.1572x; 1.1572x over previous
//
#include <hip/hip_runtime.h>
#include <hip/hip_bf16.h>
#include <math.h>

#define D_MODEL 1024
#define LSEQ 2048
#define BATCH 2
#define NROWS (BATCH*LSEQ)   // 4096
#define NC 16                // decay-sum chunks along L
#define CHS (LSEQ/NC)        // 128

typedef __bf16 bf16;
typedef __attribute__((ext_vector_type(8))) __bf16 bf16x8;
typedef __attribute__((ext_vector_type(4))) __bf16 bf16x4;
typedef __attribute__((ext_vector_type(4))) float f32x4;

__device__ __forceinline__ float sigA(float ap) {
    return fmaxf(1.0f / (1.0f + expf(-ap)), 1e-30f);
}

// async global->LDS, 16B per lane; lds dest = wave-uniform base + lane*16
__device__ __forceinline__ void gload_lds16(const void* g, void* l) {
    __builtin_amdgcn_global_load_lds(
        (const __attribute__((address_space(1))) void*)g,
        (__attribute__((address_space(3))) void*)l, 16, 0, 0);
}

// ---------------- K1: chunked decay partial sums  P_c[b,c,d] = sum_{s in chunk c} A^s x[b,s,d]
__global__ __launch_bounds__(256) void k_decay(const float* __restrict__ x,
                                               const float* __restrict__ A_param,
                                               float* __restrict__ partial) {
    const int c = blockIdx.x, dg = blockIdx.y, b = blockIdx.z;
    const int d = dg * 256 + threadIdx.x;
    const float A = sigA(A_param[d]);
    const float l2A = log2f(A);
    const int s0 = c * CHS;
    float sum = 0.0f;
    float w = exp2f((float)s0 * l2A);   // if chunk's largest weight underflows, chunk is exactly 0
    if (w != 0.0f) {
        const float* xp = x + ((size_t)b * LSEQ + s0) * D_MODEL + d;
        for (int j = 0; j < CHS; ++j) {
            sum += w * xp[(size_t)j * D_MODEL];
            w *= A;
        }
    }
    partial[((size_t)b * NC + c) * D_MODEL + d] = sum;
}

// ---------------- K2: W f32 -> bf16
__global__ __launch_bounds__(256) void k_wcast(const float* __restrict__ W, bf16* __restrict__ Wb) {
    int idx = (blockIdx.x * 256 + threadIdx.x) * 4;   // D*D = 1M, exact
    f32x4 v = *reinterpret_cast<const f32x4*>(W + idx);
    bf16x4 o;
    #pragma unroll
    for (int k = 0; k < 4; ++k) o[k] = (bf16)v[k];
    *reinterpret_cast<bf16x4*>(Wb + idx) = o;
}

// ---------------- K3: conv closed-form + skip + exact GELU -> bf16 G (GEMM A-matrix)
// thread owns 4 consecutive d; float4 x loads; w-recurrence instead of per-i exp2f
__global__ __launch_bounds__(256) void k_prep(const float* __restrict__ x,
                                              const float* __restrict__ A_param,
                                              const float* __restrict__ Bv,
                                              const float* __restrict__ Cv,
                                              const float* __restrict__ Dv,
                                              const float* __restrict__ partial,
                                              bf16* __restrict__ G) {
    const int ib = blockIdx.x, b = blockIdx.z;   // grid (LSEQ/16, 1, BATCH)
    const int i0 = ib * 16;
    const int d0 = threadIdx.x * 4;              // 256*4 = 1024 = D
    f32x4 P = {0.f, 0.f, 0.f, 0.f};
    #pragma unroll
    for (int c = 0; c < NC; ++c)
        P += *reinterpret_cast<const f32x4*>(partial + ((size_t)b * NC + c) * D_MODEL + d0);
    float A4[4], l2[4], coeff[4], dvv[4], w[4];
    #pragma unroll
    for (int k = 0; k < 4; ++k) {
        A4[k] = sigA(A_param[d0 + k]);
        l2[k] = log2f(A4[k]);
        coeff[k] = Cv[d0 + k] * Bv[d0 + k] * P[k];
        dvv[k] = Dv[d0 + k];
        // conv(i) = coeff * A^(L-1-i); start at largest i of this chunk, walk down (w grows by *A)
        w[k] = exp2f((float)(LSEQ - 1 - (i0 + 15)) * l2[k]);
    }
    for (int j = 15; j >= 0; --j) {
        const int i = i0 + j;
        f32x4 xv = *reinterpret_cast<const f32x4*>(x + ((size_t)b * LSEQ + i) * D_MODEL + d0);
        bf16x4 g;
        #pragma unroll
        for (int k = 0; k < 4; ++k) {
            float u = coeff[k] * w[k] + dvv[k] * xv[k];
            g[k] = (bf16)(0.5f * u * (1.0f + erff(u * 0.70710678118654752f)));
            w[k] *= A4[k];
        }
        *reinterpret_cast<bf16x4*>(G + ((size_t)b * LSEQ + i) * D_MODEL + d0) = g;
    }
}

// ---------------- K4: Z = bf16(x + G @ Wb^T + bias)
// TM=64 TN=128 BK=64, 4 waves (2x2), dbuf LDS + global_load_lds, 1 barrier/K-step
#define TM 64
#define TN 128
#define BKK 64
#define NT (D_MODEL / BKK)   // 16

__global__ __launch_bounds__(256) void k_gemm(const bf16* __restrict__ G,
                                              const bf16* __restrict__ Wb,
                                              const float* __restrict__ bias,
                                              const float* __restrict__ x,
                                              bf16* __restrict__ Z) {
    __shared__ __align__(16) bf16 S[2][(TM + TN) * BKK];   // 2 x 24 KiB
    const int tid = threadIdx.x;
    const int lane = tid & 63, wave = tid >> 6;
    const int row0 = blockIdx.x * TM, col0 = blockIdx.y * TN;
    const int wr = wave >> 1, wc = wave & 1;      // wave tile: 32 x 64
    const int mr = lane & 15, kr = (lane >> 4) * 8;
    const int lrow = lane >> 3, lcol = (lane & 7) * 8;   // staging: 8 rows x 64 cols per 1KB chunk
    f32x4 acc[2][4] = {};

    auto stage = [&](int buf, int k0) {
        #pragma unroll
        for (int r = 0; r < 2; ++r) {            // A tile: 64x64 bf16 = 8 chunks
            int ci = wave * 2 + r;
            gload_lds16(G + (size_t)(row0 + ci * 8 + lrow) * D_MODEL + k0 + lcol,
                        &S[buf][ci * 512]);
        }
        #pragma unroll
        for (int r = 0; r < 4; ++r) {            // B tile: 128x64 bf16 = 16 chunks
            int ci = wave * 4 + r;
            gload_lds16(Wb + (size_t)(col0 + ci * 8 + lrow) * D_MODEL + k0 + lcol,
                        &S[buf][TM * BKK + ci * 512]);
        }
    };

    stage(0, 0);
    __syncthreads();                              // drain prologue loads
    for (int t = 0; t < NT; ++t) {
        const int cur = t & 1;
        if (t + 1 < NT) stage(cur ^ 1, (t + 1) * BKK);   // next tile in flight during compute
        const bf16* sa = &S[cur][0];
        const bf16* sb = &S[cur][TM * BKK];
        bf16x8 a[2][2], bbv[4][2];
        #pragma unroll
        for (int fm = 0; fm < 2; ++fm)
            #pragma unroll
            for (int ks = 0; ks < 2; ++ks)
                a[fm][ks] = *reinterpret_cast<const bf16x8*>(sa + (wr * 32 + fm * 16 + mr) * BKK + ks * 32 + kr);
        #pragma unroll
        for (int fn = 0; fn < 4; ++fn)
            #pragma unroll
            for (int ks = 0; ks < 2; ++ks)
                bbv[fn][ks] = *reinterpret_cast<const bf16x8*>(sb + (wc * 64 + fn * 16 + mr) * BKK + ks * 32 + kr);
        #pragma unroll
        for (int fm = 0; fm < 2; ++fm)
            #pragma unroll
            for (int fn = 0; fn < 4; ++fn)
                #pragma unroll
                for (int ks = 0; ks < 2; ++ks)
                    acc[fm][fn] = __builtin_amdgcn_mfma_f32_16x16x32_bf16(a[fm][ks], bbv[fn][ks], acc[fm][fn], 0, 0, 0);
        __syncthreads();                          // drains next-tile loads (vmcnt) + guards reuse
    }
    // epilogue: C/D layout col = lane&15, row = (lane>>4)*4 + reg; fuse +bias +x, emit bf16
    #pragma unroll
    for (int fm = 0; fm < 2; ++fm) {
        const int rbase = row0 + wr * 32 + fm * 16 + (lane >> 4) * 4;
        #pragma unroll
        for (int fn = 0; fn < 4; ++fn) {
            const int c = col0 + wc * 64 + fn * 16 + mr;
            const float bv = bias[c];
            #pragma unroll
            for (int r = 0; r < 4; ++r) {
                const int rr = rbase + r;
                float z = acc[fm][fn][r] + bv + x[(size_t)rr * D_MODEL + c];
                Z[(size_t)rr * D_MODEL + c] = (bf16)z;
            }
        }
    }
}

// ---------------- K5: out = LayerNorm(Z) * gamma + beta
__global__ __launch_bounds__(256) void k_ln(const bf16* __restrict__ Z,
                                            const float* __restrict__ gamma,
                                            const float* __restrict__ beta,
                                            float* __restrict__ out) {
    const int row = blockIdx.x;
    const int t = threadIdx.x;
    bf16x4 zv = *reinterpret_cast<const bf16x4*>(Z + (size_t)row * D_MODEL + t * 4);
    float z[4];
    float s = 0.0f, sq = 0.0f;
    #pragma unroll
    for (int k = 0; k < 4; ++k) {
        z[k] = (float)zv[k];
        s += z[k]; sq += z[k] * z[k];
    }
    #pragma unroll
    for (int o = 1; o < 64; o <<= 1) { s += __shfl_xor(s, o, 64); sq += __shfl_xor(sq, o, 64); }
    __shared__ float ls[4], lq[4];
    const int wave = t >> 6;
    if ((t & 63) == 0) { ls[wave] = s; lq[wave] = sq; }
    __syncthreads();
    s = ls[0] + ls[1] + ls[2] + ls[3];
    sq = lq[0] + lq[1] + lq[2] + lq[3];
    const float mu = s * (1.0f / D_MODEL);
    const float var = sq * (1.0f / D_MODEL) - mu * mu;
    const float inv = rsqrtf(var + 1e-5f);
    f32x4 g = *reinterpret_cast<const f32x4*>(gamma + t * 4);
    f32x4 be = *reinterpret_cast<const f32x4*>(beta + t * 4);
    f32x4 o;
    #pragma unroll
    for (int k = 0; k < 4; ++k) o[k] = (z[k] - mu) * inv * g[k] + be[k];
    *reinterpret_cast<f32x4*>(out + (size_t)row * D_MODEL + t * 4) = o;
}

extern "C" void kernel_launch(void* const* d_in, const int* in_sizes, int n_in,
                              void* d_out, int out_size, void* d_ws, size_t ws_size,
                              hipStream_t stream) {
    const float* x       = (const float*)d_in[0];
    const float* A_param = (const float*)d_in[1];
    const float* B_vec   = (const float*)d_in[2];
    const float* C_vec   = (const float*)d_in[3];
    const float* D_vec   = (const float*)d_in[4];
    const float* W       = (const float*)d_in[5];
    const float* b_proj  = (const float*)d_in[6];
    const float* gamma   = (const float*)d_in[7];
    const float* beta    = (const float*)d_in[8];
    float* out = (float*)d_out;

    char* ws = (char*)d_ws;
    float* partial = (float*)ws;                                  // 128 KiB
    bf16*  Wb      = (bf16*)(ws + (128 << 10));                   // 2 MiB
    bf16*  G       = (bf16*)(ws + (128 << 10) + (2 << 20));       // 8 MiB
    bf16*  Z       = (bf16*)(ws + (128 << 10) + (10 << 20));      // 8 MiB

    hipLaunchKernelGGL(k_decay, dim3(NC, D_MODEL / 256, BATCH), dim3(256), 0, stream, x, A_param, partial);
    hipLaunchKernelGGL(k_wcast, dim3(D_MODEL * D_MODEL / 1024), dim3(256), 0, stream, W, Wb);
    hipLaunchKernelGGL(k_prep,  dim3(LSEQ / 16, 1, BATCH), dim3(256), 0, stream,
                       x, A_param, B_vec, C_vec, D_vec, partial, G);
    hipLaunchKernelGGL(k_gemm,  dim3(NROWS / TM, D_MODEL / TN), dim3(256), 0, stream, G, Wb, b_proj, x, Z);
    hipLaunchKernelGGL(k_ln,    dim3(NROWS), dim3(256), 0, stream, Z, gamma, beta, out);
}